// Round 1
// baseline (432.992 us; speedup 1.0000x reference)
//
#include <hip/hip_runtime.h>
#include <cfloat>

// Shapes (fixed by the problem): x = [32, 1, 8192, 256] fp32
// pooled/out = [32, 1, 4096, 256] fp32
#define BATCH     32
#define H_IN      8192
#define H_OUT     4096
#define W         256
#define W4        64        // W as float4
#define CH        32        // output rows per thread in kernel 1
#define BLK_PER_B 32        // kernel-1 blocks per batch (32*128 rows = 4096)

__device__ __forceinline__ float4 max3_f4(float4 a, float4 b, float4 c) {
    float4 m;
    m.x = fmaxf(a.x, fmaxf(b.x, c.x));
    m.y = fmaxf(a.y, fmaxf(b.y, c.y));
    m.z = fmaxf(a.z, fmaxf(b.z, c.z));
    m.w = fmaxf(a.w, fmaxf(b.w, c.w));
    return m;
}

// Kernel 1: maxpool along H + per-block min/max partials.
// Grid: BATCH * BLK_PER_B blocks, 256 threads.
// Thread layout: wave = rg (row group), lane = w4 column -> full-row coalescing.
__global__ __launch_bounds__(256) void pool_partial(
        const float* __restrict__ x, float* __restrict__ out,
        float* __restrict__ partial_min, float* __restrict__ partial_max) {
    const int batch = blockIdx.x >> 5;          // / BLK_PER_B
    const int blk   = blockIdx.x & 31;
    const int tid   = threadIdx.x;
    const int w4    = tid & 63;
    const int rg    = tid >> 6;                 // wave index, 0..3
    const int h0    = blk * (BLK_PER_B * 4) + rg * CH;  // blk*128 + rg*32

    const float4* xin = (const float4*)x + (size_t)batch * H_IN * W4 + w4;
    float4*       po  = (float4*)out + ((size_t)batch * H_OUT + h0) * W4 + w4;

    float lmin = FLT_MAX, lmax = -FLT_MAX;

    // rolling previous row: row 2*h0 - 1 (only h0==0 needs -inf pad)
    float4 prev;
    const int r0 = 2 * h0 - 1;
    if (r0 >= 0) prev = xin[(size_t)r0 * W4];
    else         prev = make_float4(-FLT_MAX, -FLT_MAX, -FLT_MAX, -FLT_MAX);

    #pragma unroll 4
    for (int i = 0; i < CH; ++i) {
        const int r = 2 * (h0 + i);
        float4 a = xin[(size_t)r * W4];
        float4 c = xin[(size_t)(r + 1) * W4];
        float4 m = max3_f4(prev, a, c);
        po[(size_t)i * W4] = m;
        prev = c;
        lmax = fmaxf(lmax, fmaxf(fmaxf(m.x, m.y), fmaxf(m.z, m.w)));
        lmin = fminf(lmin, fminf(fminf(m.x, m.y), fminf(m.z, m.w)));
    }

    // wave reduce (64 lanes)
    #pragma unroll
    for (int off = 32; off > 0; off >>= 1) {
        lmax = fmaxf(lmax, __shfl_down(lmax, off, 64));
        lmin = fminf(lmin, __shfl_down(lmin, off, 64));
    }
    __shared__ float smax[4], smin[4];
    const int lane = tid & 63;
    if (lane == 0) { smax[rg] = lmax; smin[rg] = lmin; }
    __syncthreads();
    if (tid == 0) {
        float bmax = smax[0], bmin = smin[0];
        #pragma unroll
        for (int i = 1; i < 4; ++i) {
            bmax = fmaxf(bmax, smax[i]);
            bmin = fminf(bmin, smin[i]);
        }
        partial_max[blockIdx.x] = bmax;
        partial_min[blockIdx.x] = bmin;
    }
}

// Kernel 2: reduce 32 partials per batch -> (mn, 1/(mx-mn)).
// Grid: BATCH blocks, 64 threads.
__global__ void reduce_partials(const float* __restrict__ pmin,
                                const float* __restrict__ pmax,
                                float* __restrict__ stats) {
    const int b = blockIdx.x;
    const int t = threadIdx.x;
    float mn = (t < BLK_PER_B) ? pmin[b * BLK_PER_B + t] : FLT_MAX;
    float mx = (t < BLK_PER_B) ? pmax[b * BLK_PER_B + t] : -FLT_MAX;
    #pragma unroll
    for (int off = 16; off > 0; off >>= 1) {
        mn = fminf(mn, __shfl_down(mn, off, 64));
        mx = fmaxf(mx, __shfl_down(mx, off, 64));
    }
    if (t == 0) {
        stats[2 * b]     = mn;
        stats[2 * b + 1] = 1.0f / (mx - mn);
    }
}

// Kernel 3: in-place normalize d_out. Grid: BATCH*256 blocks, 256 threads,
// 4 float4 per thread -> 256*256*4 = 262144 float4 = one batch.
__global__ __launch_bounds__(256) void normalize(float* __restrict__ out,
                                                 const float* __restrict__ stats) {
    const int b   = blockIdx.x >> 8;
    const int blk = blockIdx.x & 255;
    const float mn  = stats[2 * b];
    const float inv = stats[2 * b + 1];
    float4* p = (float4*)out + (size_t)b * (H_OUT * W4);
    const int base = blk * 1024 + threadIdx.x;
    #pragma unroll
    for (int i = 0; i < 4; ++i) {
        const int idx = base + i * 256;
        float4 v = p[idx];
        v.x = (v.x - mn) * inv;
        v.y = (v.y - mn) * inv;
        v.z = (v.z - mn) * inv;
        v.w = (v.w - mn) * inv;
        p[idx] = v;
    }
}

extern "C" void kernel_launch(void* const* d_in, const int* in_sizes, int n_in,
                              void* d_out, int out_size, void* d_ws, size_t ws_size,
                              hipStream_t stream) {
    const float* x   = (const float*)d_in[0];
    float*       out = (float*)d_out;
    float*       ws  = (float*)d_ws;

    float* pmin  = ws;                 // 1024 floats
    float* pmax  = ws + 1024;          // 1024 floats
    float* stats = ws + 2048;          // 64 floats

    pool_partial<<<BATCH * BLK_PER_B, 256, 0, stream>>>(x, out, pmin, pmax);
    reduce_partials<<<BATCH, 64, 0, stream>>>(pmin, pmax, stats);
    normalize<<<BATCH * 256, 256, 0, stream>>>(out, stats);
}